// Round 10
// baseline (6275.242 us; speedup 1.0000x reference)
//
#include <hip/hip_runtime.h>
#include <math.h>

#define NN 50000
#define EE 800000
#define TT 50
#define EVCAP 1150016  // 800000 + 7*50000 + slack (padded CSR capacity)
#define SB 196         // (NN + 255) / 256 scan blocks

__device__ __forceinline__ float sigm(float x)   { return 1.f / (1.f + __expf(-x)); }
__device__ __forceinline__ float tanh_f(float x) { float e = __expf(2.f * x); return 1.f - 2.f / (e + 1.f); }

// ---------------- CSR build (counting sort by row, rows padded to %8) ----------------

__global__ __launch_bounds__(256) void hist_kernel(const int* __restrict__ idx, int* __restrict__ cnt) {
    int e = blockIdx.x * blockDim.x + threadIdx.x;
    if (e < EE) atomicAdd(&cnt[idx[2 * e]], 1);
}

__global__ __launch_bounds__(256) void scan1(const int* __restrict__ cnt, int* __restrict__ rp,
                                             int* __restrict__ bsum) {
    __shared__ int s[256];
    int t = threadIdx.x;
    int g = blockIdx.x * 256 + t;
    int v = (g < NN) ? ((cnt[g] + 7) & ~7) : 0;
    s[t] = v;
    __syncthreads();
    for (int off = 1; off < 256; off <<= 1) {
        int add = (t >= off) ? s[t - off] : 0;
        __syncthreads();
        v += add;
        s[t] = v;
        __syncthreads();
    }
    if (g < NN) rp[g + 1] = v;
    if (t == 255) bsum[blockIdx.x] = v;
}

__global__ __launch_bounds__(256) void scan2(int* __restrict__ bsum) {
    __shared__ int s[256];
    int t = threadIdx.x;
    int v = (t < SB) ? bsum[t] : 0;
    s[t] = v;
    __syncthreads();
    for (int off = 1; off < 256; off <<= 1) {
        int add = (t >= off) ? s[t - off] : 0;
        __syncthreads();
        v += add;
        s[t] = v;
        __syncthreads();
    }
    if (t < SB) bsum[t] = v;
}

__global__ __launch_bounds__(256) void scan3(int* __restrict__ rp, const int* __restrict__ bsum) {
    int g = blockIdx.x * 256 + threadIdx.x;
    int off = (blockIdx.x > 0) ? bsum[blockIdx.x - 1] : 0;
    if (g < NN) rp[g + 1] += off;
    if (g == 0) rp[0] = 0;
}

// edge record: .x = col, .y = bit-cast float value. Pad slots stay (0, 0.0f) from memset.
__global__ __launch_bounds__(256) void scatter_kernel(const int* __restrict__ idx, const float* __restrict__ val,
                                                      const int* __restrict__ rp, int* __restrict__ cnt,
                                                      int2* __restrict__ ev) {
    int e = blockIdx.x * blockDim.x + threadIdx.x;
    if (e >= EE) return;
    int r = idx[2 * e];
    int p = rp[r] + atomicAdd(&cnt[r], 1);
    ev[p] = make_int2(idx[2 * e + 1], __float_as_int(val[e]));
}

// ---------------- one-time x precompute ----------------

__global__ __launch_bounds__(256) void transpose_x(const float* __restrict__ F, float* __restrict__ xT) {
    __shared__ float tile[64][51];
    int n0 = blockIdx.x * 64;
    for (int i = threadIdx.x; i < TT * 64; i += 256) {
        int t = i >> 6, n = i & 63;
        if (n0 + n < NN) tile[n][t] = F[(size_t)t * NN + n0 + n];
    }
    __syncthreads();
    for (int i = threadIdx.x; i < 64 * 64; i += 256) {
        int n = i >> 6, t = i & 63;
        if (n0 + n < NN) xT[(size_t)(n0 + n) * 64 + t] = (t < TT) ? tile[n][t] : 0.f;
    }
}

// 16-deep gather body (rows padded %8: main 16-deep + optional exact-8 tail)
#define GATH16(TBL)                                                                   \
    float a0=0.f,a1=0.f,a2=0.f,a3=0.f,a4=0.f,a5=0.f,a6=0.f,a7=0.f;                    \
    float b0=0.f,b1=0.f,b2=0.f,b3=0.f,b4=0.f,b5=0.f,b6=0.f,b7=0.f;                    \
    for (; e + 16 <= e1; e += 16) {                                                   \
        int2 q0=ev[e+0],q1=ev[e+1],q2=ev[e+2],q3=ev[e+3];                             \
        int2 q4=ev[e+4],q5=ev[e+5],q6=ev[e+6],q7=ev[e+7];                             \
        int2 r0=ev[e+8],r1=ev[e+9],r2=ev[e+10],r3=ev[e+11];                           \
        int2 r4=ev[e+12],r5=ev[e+13],r6=ev[e+14],r7=ev[e+15];                         \
        a0=fmaf(__int_as_float(q0.y),TBL[(size_t)q0.x*64],a0);                        \
        a1=fmaf(__int_as_float(q1.y),TBL[(size_t)q1.x*64],a1);                        \
        a2=fmaf(__int_as_float(q2.y),TBL[(size_t)q2.x*64],a2);                        \
        a3=fmaf(__int_as_float(q3.y),TBL[(size_t)q3.x*64],a3);                        \
        a4=fmaf(__int_as_float(q4.y),TBL[(size_t)q4.x*64],a4);                        \
        a5=fmaf(__int_as_float(q5.y),TBL[(size_t)q5.x*64],a5);                        \
        a6=fmaf(__int_as_float(q6.y),TBL[(size_t)q6.x*64],a6);                        \
        a7=fmaf(__int_as_float(q7.y),TBL[(size_t)q7.x*64],a7);                        \
        b0=fmaf(__int_as_float(r0.y),TBL[(size_t)r0.x*64],b0);                        \
        b1=fmaf(__int_as_float(r1.y),TBL[(size_t)r1.x*64],b1);                        \
        b2=fmaf(__int_as_float(r2.y),TBL[(size_t)r2.x*64],b2);                        \
        b3=fmaf(__int_as_float(r3.y),TBL[(size_t)r3.x*64],b3);                        \
        b4=fmaf(__int_as_float(r4.y),TBL[(size_t)r4.x*64],b4);                        \
        b5=fmaf(__int_as_float(r5.y),TBL[(size_t)r5.x*64],b5);                        \
        b6=fmaf(__int_as_float(r6.y),TBL[(size_t)r6.x*64],b6);                        \
        b7=fmaf(__int_as_float(r7.y),TBL[(size_t)r7.x*64],b7);                        \
    }                                                                                 \
    if (e < e1) {  /* exactly 8 left */                                               \
        int2 q0=ev[e+0],q1=ev[e+1],q2=ev[e+2],q3=ev[e+3];                             \
        int2 q4=ev[e+4],q5=ev[e+5],q6=ev[e+6],q7=ev[e+7];                             \
        a0=fmaf(__int_as_float(q0.y),TBL[(size_t)q0.x*64],a0);                        \
        a1=fmaf(__int_as_float(q1.y),TBL[(size_t)q1.x*64],a1);                        \
        a2=fmaf(__int_as_float(q2.y),TBL[(size_t)q2.x*64],a2);                        \
        a3=fmaf(__int_as_float(q3.y),TBL[(size_t)q3.x*64],a3);                        \
        a4=fmaf(__int_as_float(q4.y),TBL[(size_t)q4.x*64],a4);                        \
        a5=fmaf(__int_as_float(q5.y),TBL[(size_t)q5.x*64],a5);                        \
        a6=fmaf(__int_as_float(q6.y),TBL[(size_t)q6.x*64],a6);                        \
        a7=fmaf(__int_as_float(q7.y),TBL[(size_t)q7.x*64],a7);                        \
    }                                                                                 \
    float rsum = (((a0+a1)+(a2+a3))+((a4+a5)+(a6+a7))) + (((b0+b1)+(b2+b3))+((b4+b5)+(b6+b7)));

// SxAll[t][w] = sum_e v_e * xT[col_e][t]  (one pass for all 50 steps)
__global__ __launch_bounds__(256) void spmm_sx(const int* __restrict__ rp, const int2* __restrict__ ev,
                                               const float* __restrict__ xT, float* __restrict__ SxAll) {
    int w = __builtin_amdgcn_readfirstlane((blockIdx.x * blockDim.x + threadIdx.x) >> 6);
    int lane = threadIdx.x & 63;
    if (w >= NN) return;
    int e  = __builtin_amdgcn_readfirstlane(rp[w]);
    int e1 = __builtin_amdgcn_readfirstlane(rp[w + 1]);
    const float* xl = xT + lane;
    GATH16(xl)
    if (lane < TT) SxAll[(size_t)lane * NN + w] = rsum;
}

// ---------------- fused: S2 = A@rh (gather) + cand GEMM + h1 update + z8[0..5] ----------------

__global__ __launch_bounds__(256) void spmm_cand(const int* __restrict__ rp, const int2* __restrict__ ev,
        const float* __restrict__ rh, const float* __restrict__ Sx,
        const float* __restrict__ Wc, const float* __restrict__ bc,
        const float* __restrict__ u1, float* __restrict__ h1,
        const float* __restrict__ Wbg, const float* __restrict__ Wbc,
        const float* __restrict__ Wug, const float* __restrict__ Wuc,
        float* __restrict__ z8) {
    __shared__ float ldsW[65 * 64];   // Wc row-major: ldsW[k*64+j]
    __shared__ float ldsS[4][64];     // per-wave S2 row stage
    int t = threadIdx.x;
    for (int i = t; i < 65 * 16; i += 256)
        ((float4*)ldsW)[i] = ((const float4*)Wc)[i];
    __syncthreads();
    int lane = t & 63;
    int wv = t >> 6;
    int j = lane;
    float bj = bc[j];
    float wz0 = Wbg[j * 2], wz1 = Wbg[j * 2 + 1], wz2 = Wbc[j];
    float wz3 = Wug[j * 2], wz4 = Wug[j * 2 + 1], wz5 = Wuc[j];
    int wstride = gridDim.x * 4;
    for (int wi = blockIdx.x * 4 + wv; wi < NN; wi += wstride) {
        int w = __builtin_amdgcn_readfirstlane(wi);
        int e  = __builtin_amdgcn_readfirstlane(rp[w]);
        int e1 = __builtin_amdgcn_readfirstlane(rp[w + 1]);
        const float* xl = rh + lane;
        GATH16(xl)
        ldsS[wv][lane] = rsum;  // same-wave producer/consumer
        float acc = fmaf(Sx[w], ldsW[j], bj);
#pragma unroll 8
        for (int k = 0; k < 64; ++k)
            acc = fmaf(ldsS[wv][k], ldsW[(k + 1) * 64 + j], acc);
        float c = tanh_f(acc);
        float u  = u1[(size_t)w * 64 + j];
        float ho = h1[(size_t)w * 64 + j];
        float hn = fmaf(u, ho - c, c);  // u*h + (1-u)*c
        h1[(size_t)w * 64 + j] = hn;
        float p0 = hn * wz0, p1 = hn * wz1, p2 = hn * wz2;
        float p3 = hn * wz3, p4 = hn * wz4, p5 = hn * wz5;
#pragma unroll
        for (int off = 1; off < 64; off <<= 1) {
            p0 += __shfl_xor(p0, off);
            p1 += __shfl_xor(p1, off);
            p2 += __shfl_xor(p2, off);
            p3 += __shfl_xor(p3, off);
            p4 += __shfl_xor(p4, off);
            p5 += __shfl_xor(p5, off);
        }
        if (j == 0) {
            z8[(size_t)w * 8 + 0] = p0; z8[(size_t)w * 8 + 1] = p1; z8[(size_t)w * 8 + 2] = p2;
            z8[(size_t)w * 8 + 3] = p3; z8[(size_t)w * 8 + 4] = p4; z8[(size_t)w * 8 + 5] = p5;
        }
    }
}

// ---------------- merged1: [spmm_h -> Sh(t+1)] || [spmm8_gate2(t)] ----------------

__global__ __launch_bounds__(256) void merged1(int GA,
        const int* __restrict__ rp, const int2* __restrict__ ev,
        const float* __restrict__ h1, float* __restrict__ Sh,
        const float* __restrict__ z8,
        const float* __restrict__ hb, const float* __restrict__ hu,
        const float* __restrict__ Wbg, const float* __restrict__ bbg,
        const float* __restrict__ Wug, const float* __restrict__ bug,
        float* __restrict__ z2, float* __restrict__ g2, float* __restrict__ S3c) {
    if ((int)blockIdx.x < GA) {
        int w = __builtin_amdgcn_readfirstlane(((int)blockIdx.x * 256 + (int)threadIdx.x) >> 6);
        int lane = threadIdx.x & 63;
        if (w >= NN) return;
        int e  = __builtin_amdgcn_readfirstlane(rp[w]);
        int e1 = __builtin_amdgcn_readfirstlane(rp[w + 1]);
        const float* xl = h1 + lane;
        GATH16(xl)
        Sh[(size_t)w * 64 + lane] = rsum;
    } else {
        int gid = ((int)blockIdx.x - GA) * 256 + threadIdx.x;
        int row = gid >> 3;
        int j = gid & 7;
        if (row >= NN) return;
        int e = rp[row], e1 = rp[row + 1];
        float a0 = 0.f, a1 = 0.f, a2 = 0.f, a3 = 0.f, a4 = 0.f, a5 = 0.f, a6 = 0.f, a7 = 0.f;
        for (; e + 7 < e1; e += 8) {  // deg % 8 == 0: exact
            int2 p0 = ev[e], p1 = ev[e + 1], p2 = ev[e + 2], p3 = ev[e + 3];
            int2 p4 = ev[e + 4], p5 = ev[e + 5], p6 = ev[e + 6], p7 = ev[e + 7];
            a0 = fmaf(__int_as_float(p0.y), z8[(size_t)p0.x * 8 + j], a0);
            a1 = fmaf(__int_as_float(p1.y), z8[(size_t)p1.x * 8 + j], a1);
            a2 = fmaf(__int_as_float(p2.y), z8[(size_t)p2.x * 8 + j], a2);
            a3 = fmaf(__int_as_float(p3.y), z8[(size_t)p3.x * 8 + j], a3);
            a4 = fmaf(__int_as_float(p4.y), z8[(size_t)p4.x * 8 + j], a4);
            a5 = fmaf(__int_as_float(p5.y), z8[(size_t)p5.x * 8 + j], a5);
            a6 = fmaf(__int_as_float(p6.y), z8[(size_t)p6.x * 8 + j], a6);
            a7 = fmaf(__int_as_float(p7.y), z8[(size_t)p7.x * 8 + j], a7);
        }
        float s = ((a0 + a1) + (a2 + a3)) + ((a4 + a5) + (a6 + a7));
        if (j == 2) S3c[row * 2 + 0] = s;
        if (j == 5) S3c[row * 2 + 1] = s;
        int lane = threadIdx.x & 63;
        int base = lane & ~7;
        float s0 = __shfl(s, base + 0);
        float s1 = __shfl(s, base + 1);
        float s3 = __shfl(s, base + 3);
        float s4 = __shfl(s, base + 4);
        float s6 = __shfl(s, base + 6);
        float s7 = __shfl(s, base + 7);
        if (j == 0) {
            float rb = sigm(fmaf(s6, Wbg[128], s0) + bbg[0]);
            float ub = sigm(fmaf(s6, Wbg[129], s1) + bbg[1]);
            float ru = sigm(fmaf(s7, Wug[128], s3) + bug[0]);
            float uu = sigm(fmaf(s7, Wug[129], s4) + bug[1]);
            z2[row * 2 + 0] = rb * hb[row];
            z2[row * 2 + 1] = ru * hu[row];
            g2[row * 2 + 0] = ub;
            g2[row * 2 + 1] = uu;
        }
    }
}

// ---------------- merged2: [gate1(t)] || [spmm2_update2(t-1)] (blockDim 256) ----------------
// gate1: W1_g in named float4 registers (16/thread); S-row via wave-uniform scalar loads.

#define WLOAD(q) float4 wv##q = make_float4(Wg[(4*q+1)*128+j], Wg[(4*q+2)*128+j], \
                                            Wg[(4*q+3)*128+j], Wg[(4*q+4)*128+j])
#define SFMA(q)  { float4 s_ = srow[q]; \
                   acc = fmaf(s_.x, wv##q.x, acc); acc = fmaf(s_.y, wv##q.y, acc); \
                   acc = fmaf(s_.z, wv##q.z, acc); acc = fmaf(s_.w, wv##q.w, acc); }

__global__ __launch_bounds__(256) void merged2(int GA,
        const float* __restrict__ Sh, const float* __restrict__ Sx,
        const float* __restrict__ Wg, const float* __restrict__ bg,
        const float* __restrict__ h1, float* __restrict__ rh, float* __restrict__ u1,
        const int* __restrict__ rp, const int2* __restrict__ ev,
        const float* __restrict__ z2, const float* __restrict__ S3c, const float* __restrict__ g2,
        const float* __restrict__ Wbc, const float* __restrict__ bbc,
        const float* __restrict__ Wuc, const float* __restrict__ buc,
        float* __restrict__ hb, float* __restrict__ hu,
        float* __restrict__ z8, float* __restrict__ out, int tPrev) {
    if ((int)blockIdx.x < GA) {
        int j = threadIdx.x & 127;     // output column
        int g = threadIdx.x >> 7;      // node stream 0/1 (wave-uniform)
        float w0 = Wg[j];
        float bj = bg[j];
        WLOAD(0);  WLOAD(1);  WLOAD(2);  WLOAD(3);
        WLOAD(4);  WLOAD(5);  WLOAD(6);  WLOAD(7);
        WLOAD(8);  WLOAD(9);  WLOAD(10); WLOAD(11);
        WLOAD(12); WLOAD(13); WLOAD(14); WLOAD(15);
        for (int n = (int)blockIdx.x * 2 + g; n < NN; n += GA * 2) {
            int nn = __builtin_amdgcn_readfirstlane(n);
            const float4* srow = (const float4*)(Sh + (size_t)nn * 64);
            float acc = fmaf(Sx[nn], w0, bj);
            SFMA(0);  SFMA(1);  SFMA(2);  SFMA(3);
            SFMA(4);  SFMA(5);  SFMA(6);  SFMA(7);
            SFMA(8);  SFMA(9);  SFMA(10); SFMA(11);
            SFMA(12); SFMA(13); SFMA(14); SFMA(15);
            float gg = sigm(acc);
            if (j < 64) rh[(size_t)nn * 64 + j] = gg * h1[(size_t)nn * 64 + j];
            else        u1[(size_t)nn * 64 + (j - 64)] = gg;
        }
    } else {
        int gid = ((int)blockIdx.x - GA) * 256 + threadIdx.x;
        int row = gid >> 1;
        int j = gid & 1;
        if (row >= NN) return;
        int e = rp[row], e1 = rp[row + 1];
        float a0 = 0.f, a1 = 0.f, a2 = 0.f, a3 = 0.f, a4 = 0.f, a5 = 0.f, a6 = 0.f, a7 = 0.f;
        for (; e + 7 < e1; e += 8) {  // deg % 8 == 0: exact
            int2 p0 = ev[e], p1 = ev[e + 1], p2 = ev[e + 2], p3 = ev[e + 3];
            int2 p4 = ev[e + 4], p5 = ev[e + 5], p6 = ev[e + 6], p7 = ev[e + 7];
            a0 = fmaf(__int_as_float(p0.y), z2[(size_t)p0.x * 2 + j], a0);
            a1 = fmaf(__int_as_float(p1.y), z2[(size_t)p1.x * 2 + j], a1);
            a2 = fmaf(__int_as_float(p2.y), z2[(size_t)p2.x * 2 + j], a2);
            a3 = fmaf(__int_as_float(p3.y), z2[(size_t)p3.x * 2 + j], a3);
            a4 = fmaf(__int_as_float(p4.y), z2[(size_t)p4.x * 2 + j], a4);
            a5 = fmaf(__int_as_float(p5.y), z2[(size_t)p5.x * 2 + j], a5);
            a6 = fmaf(__int_as_float(p6.y), z2[(size_t)p6.x * 2 + j], a6);
            a7 = fmaf(__int_as_float(p7.y), z2[(size_t)p7.x * 2 + j], a7);
        }
        float s = ((a0 + a1) + (a2 + a3)) + ((a4 + a5) + (a6 + a7));
        int lane = threadIdx.x & 63;
        int base = lane & ~1;
        float sA = __shfl(s, base + 0);
        float sB = __shfl(s, base + 1);
        if (j == 0) {
            float cb = tanh_f(fmaf(sA, Wbc[64], S3c[row * 2 + 0]) + bbc[0]);
            float cu = tanh_f(fmaf(sB, Wuc[64], S3c[row * 2 + 1]) + buc[0]);
            float ub = g2[row * 2 + 0], uu = g2[row * 2 + 1];
            float hbn = fmaf(ub, hb[row] - cb, cb);
            float hun = fmaf(uu, hu[row] - cu, cu);
            hb[row] = hbn; hu[row] = hun;
            z8[(size_t)row * 8 + 6] = hbn;
            z8[(size_t)row * 8 + 7] = hun;
            out[(size_t)tPrev * NN + row] = hbn;
            out[(size_t)(TT + tPrev) * NN + row] = hun;
        }
    }
}

// ---------------- host ----------------

extern "C" void kernel_launch(void* const* d_in, const int* in_sizes, int n_in,
                              void* d_out, int out_size, void* d_ws, size_t ws_size,
                              hipStream_t stream) {
    const float* features = (const float*)d_in[0];
    const int*   index    = (const int*)d_in[1];
    const float* value    = (const float*)d_in[2];
    const float* W1g  = (const float*)d_in[3];
    const float* b1g  = (const float*)d_in[4];
    const float* W1c  = (const float*)d_in[5];
    const float* b1c  = (const float*)d_in[6];
    const float* W2bg = (const float*)d_in[7];
    const float* b2bg = (const float*)d_in[8];
    const float* W2bc = (const float*)d_in[9];
    const float* b2bc = (const float*)d_in[10];
    const float* W2ug = (const float*)d_in[11];
    const float* b2ug = (const float*)d_in[12];
    const float* W2uc = (const float*)d_in[13];
    const float* b2uc = (const float*)d_in[14];
    float* out = (float*)d_out;

    char* ws = (char*)d_ws;
    size_t o = 0;
    auto alloc = [&](size_t bytes) { size_t cur = o; o += (bytes + 255) & ~(size_t)255; return cur; };
    // zero-init region: h1, hb, hu, z8 (contiguous)
    size_t o_h1  = alloc((size_t)NN * 64 * 4);
    size_t o_hb  = alloc((size_t)NN * 4);
    size_t o_hu  = alloc((size_t)NN * 4);
    size_t o_z8  = alloc((size_t)NN * 8 * 4);
    size_t zeroEnd = o;
    size_t o_rp  = alloc((size_t)(NN + 1) * 4);
    size_t o_cnt = alloc((size_t)NN * 4);
    size_t o_bs  = alloc((size_t)256 * 4);
    size_t o_ev  = alloc((size_t)EVCAP * 8);
    size_t o_Sh  = alloc((size_t)NN * 64 * 4);
    size_t o_SxA = alloc((size_t)TT * NN * 4);
    size_t o_rh  = alloc((size_t)NN * 64 * 4);  // doubles as xT during setup
    size_t o_u1  = alloc((size_t)NN * 64 * 4);
    size_t o_S3c = alloc((size_t)NN * 2 * 4);
    size_t o_z2  = alloc((size_t)NN * 2 * 4);
    size_t o_g2  = alloc((size_t)NN * 2 * 4);
    (void)ws_size; (void)in_sizes; (void)n_in; (void)out_size;

    float* h1  = (float*)(ws + o_h1);
    float* hb  = (float*)(ws + o_hb);
    float* hu  = (float*)(ws + o_hu);
    float* z8  = (float*)(ws + o_z8);
    int*   rp  = (int*)(ws + o_rp);
    int*   cnt = (int*)(ws + o_cnt);
    int*   bsum = (int*)(ws + o_bs);
    int2*  ev  = (int2*)(ws + o_ev);
    float* Sh  = (float*)(ws + o_Sh);
    float* SxA = (float*)(ws + o_SxA);
    float* rh  = (float*)(ws + o_rh);
    float* u1  = (float*)(ws + o_u1);
    float* S3c = (float*)(ws + o_S3c);
    float* z2  = (float*)(ws + o_z2);
    float* g2  = (float*)(ws + o_g2);
    float* xT  = rh;  // alias: only used before gate1(t=0)

    // CSR build (rows padded to multiple of 8; pad slots are (0, 0.0f))
    (void)hipMemsetAsync(ws + o_cnt, 0, (size_t)NN * 4, stream);
    hist_kernel<<<(EE + 255) / 256, 256, 0, stream>>>(index, cnt);
    scan1<<<SB, 256, 0, stream>>>(cnt, rp, bsum);
    scan2<<<1, 256, 0, stream>>>(bsum);
    scan3<<<SB, 256, 0, stream>>>(rp, bsum);
    (void)hipMemsetAsync(ws + o_cnt, 0, (size_t)NN * 4, stream);
    (void)hipMemsetAsync(ws + o_ev, 0, (size_t)EVCAP * 8, stream);
    scatter_kernel<<<(EE + 255) / 256, 256, 0, stream>>>(index, value, rp, cnt, ev);

    // zero states + Sh(0) (h1(0)=0 => A@h1=0)
    (void)hipMemsetAsync(ws + o_h1, 0, zeroEnd - o_h1, stream);
    (void)hipMemsetAsync(ws + o_Sh, 0, (size_t)NN * 64 * 4, stream);

    // one-time x precompute: SxA[t][n] = (A @ x_t)[n]
    transpose_x<<<(NN + 63) / 64, 256, 0, stream>>>(features, xT);
    spmm_sx<<<(NN + 3) / 4, 256, 0, stream>>>(rp, ev, xT, SxA);

    const int GA1 = (NN + 3) / 4;            // 12500 blocks (spmm_h)
    const int GB1 = (NN * 8 + 255) / 256;    // 1563 blocks (spmm8_gate2)
    const int GA2 = 1024;                    // gate1 blocks (2 node streams each)
    const int GB2 = (NN * 2 + 255) / 256;    // 391 blocks (spmm2_update2)

    for (int t = 0; t < TT; ++t) {
        const float* Sxt = SxA + (size_t)t * NN;
        // gate1(t)  ||  spmm2_update2(t-1)
        int g2grid = (t > 0) ? (GA2 + GB2) : GA2;
        merged2<<<g2grid, 256, 0, stream>>>(GA2, Sh, Sxt, W1g, b1g, h1, rh, u1,
                                            rp, ev, z2, S3c, g2, W2bc, b2bc, W2uc, b2uc,
                                            hb, hu, z8, out, t - 1);
        // S2-gather + candidate + h1 update + z8[0..5], fused
        spmm_cand<<<2048, 256, 0, stream>>>(rp, ev, rh, Sxt, W1c, b1c, u1, h1,
                                            W2bg, W2bc, W2ug, W2uc, z8);
        // spmm_h -> Sh(t+1)  ||  spmm8_gate2(t)
        int gA = (t < TT - 1) ? GA1 : 0;
        merged1<<<gA + GB1, 256, 0, stream>>>(gA, rp, ev, h1, Sh,
                                              z8, hb, hu, W2bg, b2bg, W2ug, b2ug, z2, g2, S3c);
    }
    // final spmm2_update2(t=49)
    merged2<<<GB2, 256, 0, stream>>>(0, Sh, SxA, W1g, b1g, h1, rh, u1,
                                     rp, ev, z2, S3c, g2, W2bc, b2bc, W2uc, b2uc,
                                     hb, hu, z8, out, TT - 1);
}